// Round 6
// baseline (999.289 us; speedup 1.0000x reference)
//
#include <hip/hip_runtime.h>
#include <hip/hip_bf16.h>
#include <stdint.h>

typedef __attribute__((ext_vector_type(4))) float f32x4;
typedef __attribute__((ext_vector_type(8))) short short8;
typedef __attribute__((ext_vector_type(4))) short short4v;

#define CDIV(a, b) (((a) + (b) - 1) / (b))

__device__ __forceinline__ unsigned short f2bf(float x) {
  union { float f; unsigned int u; } c; c.f = x;
  unsigned int r = c.u + 0x7FFFu + ((c.u >> 16) & 1u);   // round-to-nearest-even
  return (unsigned short)(r >> 16);
}
__device__ __forceinline__ unsigned short f2bf_hw(float x) {
  __hip_bfloat16 h = __float2bfloat16(x);                // pairs fuse into v_cvt_pk_bf16_f32
  unsigned short u; __builtin_memcpy(&u, &h, 2); return u;
}
__device__ __forceinline__ float bf2f(unsigned short b) {
  union { unsigned int u; float f; } c; c.u = (unsigned int)b << 16; return c.f;
}

// counted vmcnt wait (compile-time immediate)
template<int N> __device__ __forceinline__ void wait_vm() {
  static_assert(N >= 0 && N <= 15, "vmcnt imm");
  if constexpr (N == 0)  asm volatile("s_waitcnt vmcnt(0)" ::: "memory");
  else if constexpr (N == 1)  asm volatile("s_waitcnt vmcnt(1)" ::: "memory");
  else if constexpr (N == 2)  asm volatile("s_waitcnt vmcnt(2)" ::: "memory");
  else if constexpr (N == 3)  asm volatile("s_waitcnt vmcnt(3)" ::: "memory");
  else if constexpr (N == 4)  asm volatile("s_waitcnt vmcnt(4)" ::: "memory");
  else if constexpr (N == 5)  asm volatile("s_waitcnt vmcnt(5)" ::: "memory");
  else if constexpr (N == 6)  asm volatile("s_waitcnt vmcnt(6)" ::: "memory");
  else if constexpr (N == 7)  asm volatile("s_waitcnt vmcnt(7)" ::: "memory");
  else if constexpr (N == 8)  asm volatile("s_waitcnt vmcnt(8)" ::: "memory");
  else if constexpr (N == 9)  asm volatile("s_waitcnt vmcnt(9)" ::: "memory");
  else if constexpr (N == 10) asm volatile("s_waitcnt vmcnt(10)" ::: "memory");
  else if constexpr (N == 11) asm volatile("s_waitcnt vmcnt(11)" ::: "memory");
  else if constexpr (N == 12) asm volatile("s_waitcnt vmcnt(12)" ::: "memory");
  else                        asm volatile("s_waitcnt vmcnt(15)" ::: "memory");
}
__device__ __forceinline__ void wait_all() {
  asm volatile("s_waitcnt vmcnt(0) lgkmcnt(0)" ::: "memory");
}
__device__ __forceinline__ void raw_barrier() {
  __builtin_amdgcn_sched_barrier(0);
  __builtin_amdgcn_s_barrier();
  asm volatile("" ::: "memory");
  __builtin_amdgcn_sched_barrier(0);
}

// async global->LDS, 16B per lane; LDS dest must be wave-uniform base + lane*16 (linear)
__device__ __forceinline__ void gl2lds16(const void* g, void* lds) {
  __builtin_amdgcn_global_load_lds(
      reinterpret_cast<const __attribute__((address_space(1))) unsigned int*>(
          reinterpret_cast<uintptr_t>(g)),
      reinterpret_cast<__attribute__((address_space(3))) unsigned int*>(
          reinterpret_cast<uintptr_t>(lds)),
      16, 0, 0);
}

// ---------------- weight transpose: W[K][N] f32 -> Wt[N][Kpad] bf16, zero-padded ----------------
__global__ void transpose_w(const float* __restrict__ W, unsigned short* __restrict__ Wt,
                            int K, int N, int Kpad) {
  __shared__ float tile[32][33];
  int kb = blockIdx.x * 32, nb = blockIdx.y * 32;
  int tx = threadIdx.x & 31, ty = threadIdx.x >> 5;  // 256 threads = 32x8
  for (int r = ty; r < 32; r += 8) {
    int k = kb + r, n = nb + tx;
    tile[r][tx] = (k < K && n < N) ? W[(size_t)k * N + n] : 0.f;
  }
  __syncthreads();
  for (int r = ty; r < 32; r += 8) {
    int n = nb + r, k = kb + tx;
    if (n < N && k < Kpad) Wt[(size_t)n * Kpad + k] = f2bf(tile[tx][r]);
  }
}

// ---------------- graph prep ----------------
__global__ void zero_i32(int* __restrict__ p, int n) {
  int i = blockIdx.x * blockDim.x + threadIdx.x;
  if (i < n) p[i] = 0;
}

__global__ void deg_init(int* __restrict__ a, int* __restrict__ b, int n) {
  int i = blockIdx.x * blockDim.x + threadIdx.x;
  if (i < n) { a[i] = 1; b[i] = 1; }   // self-loop
}

__global__ void deg_hist(const int* __restrict__ ei, int E, int* __restrict__ deg, int n) {
  int e = blockIdx.x * blockDim.x + threadIdx.x;
  if (e >= E) return;
  unsigned int d = (unsigned int)ei[(size_t)E + e];
  if (d < (unsigned int)n) atomicAdd(&deg[d], 1);
}

__global__ void dinv_k(const int* __restrict__ deg, float* __restrict__ dinv, int n) {
  int i = blockIdx.x * blockDim.x + threadIdx.x;
  if (i < n) dinv[i] = rsqrtf((float)deg[i]);
}

// exclusive scan of (deg-1) -> row_ptr[0..n], single block of 1024, shfl-based
__global__ void scan_rowptr(const int* __restrict__ deg, int* __restrict__ rp, int n) {
  __shared__ int wsum[16];
  __shared__ int carry_s;
  const int tid = threadIdx.x, lane = tid & 63, w = tid >> 6;
  if (tid == 0) carry_s = 0;
  __syncthreads();
  for (int base = 0; base < n; base += 1024) {
    int i = base + tid;
    int d = (i < n) ? (deg[i] - 1) : 0;
    int v = d;
    #pragma unroll
    for (int off = 1; off < 64; off <<= 1) {
      int t = __shfl_up(v, off, 64);
      if (lane >= off) v += t;
    }
    if (lane == 63) wsum[w] = v;
    __syncthreads();
    int carry = carry_s;
    if (w == 0) {
      int s = (lane < 16) ? wsum[lane] : 0;
      #pragma unroll
      for (int off = 1; off < 16; off <<= 1) {
        int t = __shfl_up(s, off, 64);
        if (lane >= off) s += t;
      }
      if (lane < 16) wsum[lane] = s;
    }
    __syncthreads();
    int woff = (w > 0) ? wsum[w - 1] : 0;
    if (i < n) rp[i] = carry + woff + v - d;
    if (tid == 0) carry_s = carry + wsum[15];
    __syncthreads();
  }
  if (threadIdx.x == 0) rp[n] = carry_s;
}

__global__ void csr_fill(const int* __restrict__ ei, int E,
                         const int* __restrict__ row_ptr, int* __restrict__ cursor,
                         const float* __restrict__ dinv,
                         int* __restrict__ csr_src, float* __restrict__ csr_nrm, int n) {
  int e = blockIdx.x * blockDim.x + threadIdx.x;
  if (e >= E) return;
  unsigned int s = (unsigned int)ei[e];
  unsigned int d = (unsigned int)ei[(size_t)E + e];
  if (s >= (unsigned int)n || d >= (unsigned int)n) return;
  int pos = row_ptr[d] + atomicAdd(&cursor[d], 1);
  csr_src[pos] = (int)s;
  csr_nrm[pos] = dinv[s] * dinv[d];
}

// ---------------- GEMM: C[M,BN] = A[M,K] @ Wt[BN,Kpad]^T, full-N tile, BK=64 ----
// 2-phase pipeline with RAW s_barrier + counted vmcnt: STAGE(t+1) -> compute(t)
// -> [AMODE2: vmcnt(BIT), writeA] -> vmcnt(0)+lgkm(0) -> s_barrier -> flip.
// AMODE 1: A bf16 via gl2lds. AMODE 2: A f32 -> regs -> cvt -> ds_write. K must be %8.
template<int BM, int BN, int TH, int WN, int AMODE, bool ADD_BIAS, bool DO_RELU>
__global__ __launch_bounds__(TH, 2)
void gemm5(const void* __restrict__ Av, const unsigned short* __restrict__ Bt,
           const float* __restrict__ bias, unsigned short* __restrict__ C,
           int M, int K, int Kpad) {
  constexpr int BK = 64;
  constexpr int WCOLS = BN / WN;
  constexpr int FM = BM / 16, FN = WCOLS / 16;
  constexpr int AIT = (BM * 8) / TH;      // A staging insts (gl2lds) or reg-pairs per thread
  constexpr int BIT = (BN * 8) / TH;      // B gl2lds insts per thread
  static_assert(WN * 64 == TH, "wave grid");
  static_assert((BM * 8) % TH == 0 && (BN * 8) % TH == 0, "staging divisibility");

  __shared__ __align__(16) unsigned short Alds[2][BM * BK];
  __shared__ __align__(16) unsigned short Blds[2][BN * BK];

  const int tid = threadIdx.x;
  const int wid = tid >> 6, lane = tid & 63;   // WM=1 -> wid == wn
  const int kg = lane >> 4, lr = lane & 15;
  const int sx = lr & 7;
  const int gm = blockIdx.x * BM;

  f32x4 acc[FM][FN] = {};
  f32x4 areg[AIT][2];                          // AMODE 2 staging regs

  auto issueA = [&](int k0) {                  // fixed 2*AIT vector loads (clamped, no divergent count)
    const float* A = (const float*)Av;
    #pragma unroll
    for (int it = 0; it < AIT; ++it) {
      int q = it * TH + tid;
      int r = q >> 3, s = q & 7;
      int grow = gm + r; if (grow > M - 1) grow = M - 1;
      int kbase = k0 + (s << 3);
      int kc = (kbase + 8 <= K) ? kbase : (K - 8);
      const float* ap = A + (size_t)grow * K + kc;
      areg[it][0] = *(const f32x4*)ap;
      areg[it][1] = *(const f32x4*)(ap + 4);
    }
  };
  auto writeA = [&](int buf, int k0) {         // cvt + swizzled ds_write (zero-mask K tail)
    #pragma unroll
    for (int it = 0; it < AIT; ++it) {
      int q = it * TH + tid;
      int r = q >> 3, s = q & 7;
      int kbase = k0 + (s << 3);
      short8 b;
      #pragma unroll
      for (int i = 0; i < 4; i++) {
        b[i]     = (short)f2bf_hw(areg[it][0][i]);
        b[i + 4] = (short)f2bf_hw(areg[it][1][i]);
      }
      if (kbase + 8 > K) {                     // K%8==0 -> whole slot out of range
        #pragma unroll
        for (int i = 0; i < 8; i++) b[i] = 0;
      }
      *(short8*)(&Alds[buf][(r * 8 + (s ^ (r & 7))) * 8]) = b;
    }
  };
  auto stageA_lds = [&](int buf, int k0) {     // bf16 A via gl2lds (K%64==0 for AMODE1 users)
    const unsigned short* A = (const unsigned short*)Av;
    #pragma unroll
    for (int it = 0; it < AIT; ++it) {
      int q = it * TH + tid;
      int r = q >> 3, s = q & 7;
      int grow = gm + r; if (grow > M - 1) grow = M - 1;
      gl2lds16(A + (size_t)grow * K + k0 + ((s ^ (r & 7)) << 3), &Alds[buf][q * 8]);
    }
  };
  auto stageB = [&](int buf, int k0) {
    #pragma unroll
    for (int it = 0; it < BIT; ++it) {
      int q = it * TH + tid;
      int r = q >> 3, s = q & 7;
      gl2lds16(Bt + (size_t)r * Kpad + k0 + ((s ^ (r & 7)) << 3), &Blds[buf][q * 8]);
    }
  };
  auto compute = [&](int buf) {
    #pragma unroll
    for (int ks = 0; ks < 2; ++ks) {
      const int k8 = ks * 4 + kg;
      short8 af[FM], bq[FN];
      #pragma unroll
      for (int m = 0; m < FM; m++) {
        int r = m * 16 + lr;
        af[m] = *(const short8*)(&Alds[buf][(r * 8 + (k8 ^ sx)) * 8]);
      }
      #pragma unroll
      for (int n2 = 0; n2 < FN; n2++) {
        int cc = wid * WCOLS + n2 * 16 + lr;
        bq[n2] = *(const short8*)(&Blds[buf][(cc * 8 + (k8 ^ sx)) * 8]);
      }
      #pragma unroll
      for (int m = 0; m < FM; m++)
        #pragma unroll
        for (int n2 = 0; n2 < FN; n2++)
          acc[m][n2] = __builtin_amdgcn_mfma_f32_16x16x32_bf16(af[m], bq[n2], acc[m][n2], 0, 0, 0);
    }
  };

  // ---- prologue: stage tile 0 into buf 0 ----
  if constexpr (AMODE == 2) {
    issueA(0);
    stageB(0, 0);
    wait_vm<BIT>();                      // A regs landed (B gl2lds may still fly)
    __builtin_amdgcn_sched_barrier(0);
    writeA(0, 0);
    wait_all();                          // B in LDS + ds_writes drained
  } else {
    stageA_lds(0, 0);
    stageB(0, 0);
    wait_all();
  }
  raw_barrier();

  const int nkt = Kpad / BK;
  int cur = 0;
  for (int kt = 0; kt < nkt; ++kt) {
    const bool more = (kt + 1 < nkt);
    const int k0n = (kt + 1) * BK;
    // ---- issue next tile's staging, then compute current (loads fly under MFMA) ----
    if (more) {
      if constexpr (AMODE == 2) issueA(k0n);
      stageB(cur ^ 1, k0n);
      if constexpr (AMODE == 1) stageA_lds(cur ^ 1, k0n);
    }
    compute(cur);
    if (more) {
      if constexpr (AMODE == 2) {
        wait_vm<BIT>();                  // exactly: A(t+1) regs done, B(t+1) still in flight
        __builtin_amdgcn_sched_barrier(0);
        writeA(cur ^ 1, k0n);
      }
      wait_all();                        // drain B(t+1) gl2lds + A ds_writes AFTER compute
      raw_barrier();
      cur ^= 1;
    }
  }
  // ---- epilogue: C/D layout col=lane&15, row=(lane>>4)*4+reg ----
  #pragma unroll
  for (int m = 0; m < FM; m++) {
    #pragma unroll
    for (int jj = 0; jj < 4; jj++) {
      int grow = gm + m * 16 + kg * 4 + jj;
      if (grow < M) {
        #pragma unroll
        for (int n2 = 0; n2 < FN; n2++) {
          int gcol = wid * WCOLS + n2 * 16 + lr;
          float v = acc[m][n2][jj];
          if constexpr (ADD_BIAS) v += bias[gcol];
          if constexpr (DO_RELU) v = fmaxf(v, 0.f);
          C[(size_t)grow * BN + gcol] = f2bf(v);
        }
      }
    }
  }
}

// ---------------- GCN scatter (gather-by-dst via CSR), vectorized short4 ----------------
// Thread owns 4 cols. MODE 0: out = w*val ; MODE 1: out = part + (1-w)*val
template<int F, int LDH, bool DO_RELU, int MODE, bool OUT_BF16, bool PART_BF16>
__global__ __launch_bounds__(256)
void scatter_v(const unsigned short* __restrict__ h, const int* __restrict__ rp,
               const int* __restrict__ csrc, const float* __restrict__ cnrm,
               const float* __restrict__ dinv, const float* __restrict__ bias,
               const float* __restrict__ wptr, const void* __restrict__ part,
               void* __restrict__ outp, int n) {
  constexpr int TPN = F / 4;                    // threads per node
  const int tid = threadIdx.x;
  const int node = blockIdx.x * (256 / TPN) + tid / TPN;
  const int c4 = (tid % TPN) * 4;
  if (node >= n) return;
  float di = dinv[node];
  float sc = di * di;
  f32x4 acc;
  {
    short4v v = *(const short4v*)(h + (size_t)node * LDH + c4);
    acc[0] = sc * bf2f((unsigned short)v[0]);
    acc[1] = sc * bf2f((unsigned short)v[1]);
    acc[2] = sc * bf2f((unsigned short)v[2]);
    acc[3] = sc * bf2f((unsigned short)v[3]);
  }
  const int e1 = rp[node + 1];
  for (int e = rp[node]; e < e1; ++e) {
    int s = csrc[e];
    float nm = cnrm[e];
    short4v v = *(const short4v*)(h + (size_t)s * LDH + c4);
    acc[0] += nm * bf2f((unsigned short)v[0]);
    acc[1] += nm * bf2f((unsigned short)v[1]);
    acc[2] += nm * bf2f((unsigned short)v[2]);
    acc[3] += nm * bf2f((unsigned short)v[3]);
  }
  f32x4 bv = *(const f32x4*)(bias + c4);
  float w = *wptr;
  size_t idx = (size_t)node * F + c4;
  f32x4 r;
  #pragma unroll
  for (int i = 0; i < 4; i++) {
    float v = acc[i] + bv[i];
    if constexpr (DO_RELU) v = fmaxf(v, 0.f);
    if constexpr (MODE == 0) r[i] = w * v;
    else {
      float pv;
      if constexpr (PART_BF16) pv = bf2f(((const unsigned short*)part)[idx + i]);
      else pv = ((const float*)part)[idx + i];
      r[i] = pv + (1.f - w) * v;
    }
  }
  if constexpr (OUT_BF16) {
    short4v o;
    o[0] = (short)f2bf(r[0]); o[1] = (short)f2bf(r[1]);
    o[2] = (short)f2bf(r[2]); o[3] = (short)f2bf(r[3]);
    *(short4v*)((unsigned short*)outp + idx) = o;
  } else {
    *(f32x4*)((float*)outp + idx) = r;
  }
}

// ---------------- host ----------------
extern "C" void kernel_launch(void* const* d_in, const int* in_sizes, int n_in,
                              void* d_out, int out_size, void* d_ws, size_t ws_size,
                              hipStream_t stream) {
  const float* gene  = (const float*)d_in[0];
  const float* img   = (const float*)d_in[1];
  const int* ei_ge = (const int*)d_in[2];   // integers arrive as int32
  const int* ei_sp = (const int*)d_in[3];
  const float* W_fc1 = (const float*)d_in[4];  const float* b_fc1 = (const float*)d_in[5];
  const float* W_fc2 = (const float*)d_in[6];  const float* b_fc2 = (const float*)d_in[7];
  const float* W_g11 = (const float*)d_in[8];  const float* b_g11 = (const float*)d_in[9];
  const float* W_g12 = (const float*)d_in[10]; const float* b_g12 = (const float*)d_in[11];
  const float* W_g21 = (const float*)d_in[12]; const float* b_g21 = (const float*)d_in[13];
  const float* W_g22 = (const float*)d_in[14]; const float* b_g22 = (const float*)d_in[15];
  const float* w1p   = (const float*)d_in[16];
  const float* w2p   = (const float*)d_in[17];

  const int Nn = 50000;
  const int E_ge = in_sizes[2] / 2;
  const int E_sp = in_sizes[3] / 2;
  const int NB = CDIV(Nn, 64);               // 782 M-tiles of 64

  char* ws = (char*)d_ws;
  size_t off = 0;
  auto alloc = [&](size_t bytes) -> void* {
    void* p = ws + off;
    off += (bytes + 255) & ~(size_t)255;
    return p;
  };

  unsigned short* Wt1  = (unsigned short*)alloc((size_t)512 * 3008 * 2);
  unsigned short* Wt2  = (unsigned short*)alloc((size_t)512 * 1024 * 2);
  unsigned short* Wt11 = (unsigned short*)alloc((size_t)256 * 512 * 2);
  unsigned short* Wt12 = (unsigned short*)alloc((size_t)256 * 512 * 2);
  unsigned short* WtC  = (unsigned short*)alloc((size_t)128 * 256 * 2);  // [W_g21 | W_g22] rows
  int*   deg_sp  = (int*)alloc((size_t)Nn * 4);
  int*   deg_ge  = (int*)alloc((size_t)Nn * 4);
  float* dinv_sp = (float*)alloc((size_t)Nn * 4);
  float* dinv_ge = (float*)alloc((size_t)Nn * 4);
  int*   rp_sp   = (int*)alloc((size_t)(Nn + 1) * 4);
  int*   rp_ge   = (int*)alloc((size_t)(Nn + 1) * 4);
  int*   cursor  = (int*)alloc((size_t)Nn * 4);
  int*   csrc_sp = (int*)alloc((size_t)E_sp * 4);
  float* cnrm_sp = (float*)alloc((size_t)E_sp * 4);
  int*   csrc_ge = (int*)alloc((size_t)E_ge * 4);
  float* cnrm_ge = (float*)alloc((size_t)E_ge * 4);
  unsigned short* xbuf  = (unsigned short*)alloc((size_t)Nn * 512 * 2);  // x1 / x2, later Xc
  unsigned short* tmp   = (unsigned short*)alloc((size_t)Nn * 256 * 2);  // GEMM out pre-scatter (bf16)
  unsigned short* xpart = (unsigned short*)alloc((size_t)Nn * 256 * 2);  // bf16 part; fp32 64-col part fits
  unsigned short* Xc = xbuf;
  unsigned short* tmp2 = tmp;
  (void)ws_size; (void)n_in; (void)out_size;

  // 1. weight transposes (bf16, K zero-padded)
  transpose_w<<<dim3(94, 16), 256, 0, stream>>>(W_fc1, Wt1, 3000, 512, 3008);
  transpose_w<<<dim3(32, 16), 256, 0, stream>>>(W_fc2, Wt2, 1024, 512, 1024);
  transpose_w<<<dim3(16, 8),  256, 0, stream>>>(W_g11, Wt11, 512, 256, 512);
  transpose_w<<<dim3(16, 8),  256, 0, stream>>>(W_g12, Wt12, 512, 256, 512);
  transpose_w<<<dim3(8, 2),   256, 0, stream>>>(W_g21, WtC, 256, 64, 256);
  transpose_w<<<dim3(8, 2),   256, 0, stream>>>(W_g22, WtC + (size_t)64 * 256, 256, 64, 256);

  // 2. graph prep
  deg_init<<<CDIV(Nn, 256), 256, 0, stream>>>(deg_sp, deg_ge, Nn);
  deg_hist<<<CDIV(E_sp, 256), 256, 0, stream>>>(ei_sp, E_sp, deg_sp, Nn);
  deg_hist<<<CDIV(E_ge, 256), 256, 0, stream>>>(ei_ge, E_ge, deg_ge, Nn);
  dinv_k<<<CDIV(Nn, 256), 256, 0, stream>>>(deg_sp, dinv_sp, Nn);
  dinv_k<<<CDIV(Nn, 256), 256, 0, stream>>>(deg_ge, dinv_ge, Nn);
  scan_rowptr<<<1, 1024, 0, stream>>>(deg_sp, rp_sp, Nn);
  scan_rowptr<<<1, 1024, 0, stream>>>(deg_ge, rp_ge, Nn);
  zero_i32<<<CDIV(Nn, 256), 256, 0, stream>>>(cursor, Nn);
  csr_fill<<<CDIV(E_sp, 256), 256, 0, stream>>>(ei_sp, E_sp, rp_sp, cursor, dinv_sp, csrc_sp, cnrm_sp, Nn);
  zero_i32<<<CDIV(Nn, 256), 256, 0, stream>>>(cursor, Nn);
  csr_fill<<<CDIV(E_ge, 256), 256, 0, stream>>>(ei_ge, E_ge, rp_ge, cursor, dinv_ge, csrc_ge, cnrm_ge, Nn);

  // 3. x1 = relu(gene @ W_fc1 + b) -> bf16   (64x512 full-N, f32-A pipelined)
  gemm5<64, 512, 512, 8, 2, true, true><<<NB, 512, 0, stream>>>(
      gene, Wt1, b_fc1, xbuf, Nn, 3000, 3008);
  // 4. tmp = x1 @ W_g11 (bf16, both operands gl2lds, 64x256 full-N)
  gemm5<64, 256, 256, 4, 1, false, false><<<NB, 256, 0, stream>>>(
      xbuf, Wt11, nullptr, tmp, Nn, 512, 512);
  // 5. xpart = bf16( w1 * relu(gcn_sp(tmp) + b_g11) )
  scatter_v<256, 256, true, 0, true, false><<<Nn / 4, 256, 0, stream>>>(
      tmp, rp_sp, csrc_sp, cnrm_sp, dinv_sp, b_g11, w1p, nullptr, xpart, Nn);
  // 6. x2 = relu(img @ W_fc2 + b) -> bf16 (reuse xbuf)
  gemm5<64, 512, 512, 8, 2, true, true><<<NB, 512, 0, stream>>>(
      img, Wt2, b_fc2, xbuf, Nn, 1024, 1024);
  // 7. tmp = x2 @ W_g12
  gemm5<64, 256, 256, 4, 1, false, false><<<NB, 256, 0, stream>>>(
      xbuf, Wt12, nullptr, tmp, Nn, 512, 512);
  // 8. Xc = bf16(xpart + (1-w1) * relu(gcn_ge(tmp) + b_g12))   [Xc aliases xbuf]
  scatter_v<256, 256, true, 1, true, true><<<Nn / 4, 256, 0, stream>>>(
      tmp, rp_ge, csrc_ge, cnrm_ge, dinv_ge, b_g12, w1p, xpart, Xc, Nn);
  // 9+11. tmp2 = Xc @ [W_g21 | W_g22]  (N=128, one pass over Xc)
  gemm5<64, 128, 256, 4, 1, false, false><<<NB, 256, 0, stream>>>(
      Xc, WtC, nullptr, tmp2, Nn, 256, 256);
  // 10. xpart(fp32) = w2 * (gcn_sp(tmp2[:, 0:64]) + b_g21)
  scatter_v<64, 128, false, 0, false, false><<<Nn / 16, 256, 0, stream>>>(
      tmp2, rp_sp, csrc_sp, cnrm_sp, dinv_sp, b_g21, w2p, nullptr, (float*)xpart, Nn);
  // 12. d_out = xpart + (1-w2) * (gcn_ge(tmp2[:, 64:128]) + b_g22)
  scatter_v<64, 128, false, 1, false, false><<<Nn / 16, 256, 0, stream>>>(
      tmp2 + 64, rp_ge, csrc_ge, cnrm_ge, dinv_ge, b_g22, w2p, (float*)xpart, d_out, Nn);
}

// Round 7
// 907.520 us; speedup vs baseline: 1.1011x; 1.1011x over previous
//
#include <hip/hip_runtime.h>
#include <hip/hip_bf16.h>
#include <stdint.h>

typedef __attribute__((ext_vector_type(4))) float f32x4;
typedef __attribute__((ext_vector_type(8))) short short8;
typedef __attribute__((ext_vector_type(4))) short short4v;

#define CDIV(a, b) (((a) + (b) - 1) / (b))

__device__ __forceinline__ unsigned short f2bf(float x) {
  union { float f; unsigned int u; } c; c.f = x;
  unsigned int r = c.u + 0x7FFFu + ((c.u >> 16) & 1u);   // round-to-nearest-even
  return (unsigned short)(r >> 16);
}
__device__ __forceinline__ unsigned short f2bf_hw(float x) {
  __hip_bfloat16 h = __float2bfloat16(x);                // pairs fuse into v_cvt_pk_bf16_f32
  unsigned short u; __builtin_memcpy(&u, &h, 2); return u;
}
__device__ __forceinline__ float bf2f(unsigned short b) {
  union { unsigned int u; float f; } c; c.u = (unsigned int)b << 16; return c.f;
}

// async global->LDS, 16B per lane; LDS dest must be wave-uniform base + lane*16 (linear)
__device__ __forceinline__ void gl2lds16(const void* g, void* lds) {
  __builtin_amdgcn_global_load_lds(
      reinterpret_cast<const __attribute__((address_space(1))) unsigned int*>(
          reinterpret_cast<uintptr_t>(g)),
      reinterpret_cast<__attribute__((address_space(3))) unsigned int*>(
          reinterpret_cast<uintptr_t>(lds)),
      16, 0, 0);
}

// ---------------- weight transpose: W[K][N] f32 -> Wt[N][Kpad] bf16, zero-padded ----------------
__global__ void transpose_w(const float* __restrict__ W, unsigned short* __restrict__ Wt,
                            int K, int N, int Kpad) {
  __shared__ float tile[32][33];
  int kb = blockIdx.x * 32, nb = blockIdx.y * 32;
  int tx = threadIdx.x & 31, ty = threadIdx.x >> 5;  // 256 threads = 32x8
  for (int r = ty; r < 32; r += 8) {
    int k = kb + r, n = nb + tx;
    tile[r][tx] = (k < K && n < N) ? W[(size_t)k * N + n] : 0.f;
  }
  __syncthreads();
  for (int r = ty; r < 32; r += 8) {
    int n = nb + r, k = kb + tx;
    if (n < N && k < Kpad) Wt[(size_t)n * Kpad + k] = f2bf(tile[tx][r]);
  }
}

// ---------------- graph prep ----------------
__global__ void zero_i32(int* __restrict__ p, int n) {
  int i = blockIdx.x * blockDim.x + threadIdx.x;
  if (i < n) p[i] = 0;
}

__global__ void deg_init(int* __restrict__ a, int* __restrict__ b, int n) {
  int i = blockIdx.x * blockDim.x + threadIdx.x;
  if (i < n) { a[i] = 1; b[i] = 1; }   // self-loop
}

__global__ void deg_hist(const int* __restrict__ ei, int E, int* __restrict__ deg, int n) {
  int e = blockIdx.x * blockDim.x + threadIdx.x;
  if (e >= E) return;
  unsigned int d = (unsigned int)ei[(size_t)E + e];
  if (d < (unsigned int)n) atomicAdd(&deg[d], 1);
}

__global__ void dinv_k(const int* __restrict__ deg, float* __restrict__ dinv, int n) {
  int i = blockIdx.x * blockDim.x + threadIdx.x;
  if (i < n) dinv[i] = rsqrtf((float)deg[i]);
}

// exclusive scan of (deg-1) -> row_ptr[0..n], single block of 1024, shfl-based
__global__ void scan_rowptr(const int* __restrict__ deg, int* __restrict__ rp, int n) {
  __shared__ int wsum[16];
  __shared__ int carry_s;
  const int tid = threadIdx.x, lane = tid & 63, w = tid >> 6;
  if (tid == 0) carry_s = 0;
  __syncthreads();
  for (int base = 0; base < n; base += 1024) {
    int i = base + tid;
    int d = (i < n) ? (deg[i] - 1) : 0;
    int v = d;
    #pragma unroll
    for (int off = 1; off < 64; off <<= 1) {
      int t = __shfl_up(v, off, 64);
      if (lane >= off) v += t;
    }
    if (lane == 63) wsum[w] = v;
    __syncthreads();
    int carry = carry_s;
    if (w == 0) {
      int s = (lane < 16) ? wsum[lane] : 0;
      #pragma unroll
      for (int off = 1; off < 16; off <<= 1) {
        int t = __shfl_up(s, off, 64);
        if (lane >= off) s += t;
      }
      if (lane < 16) wsum[lane] = s;
    }
    __syncthreads();
    int woff = (w > 0) ? wsum[w - 1] : 0;
    if (i < n) rp[i] = carry + woff + v - d;
    if (tid == 0) carry_s = carry + wsum[15];
    __syncthreads();
  }
  if (threadIdx.x == 0) rp[n] = carry_s;
}

__global__ void csr_fill(const int* __restrict__ ei, int E,
                         const int* __restrict__ row_ptr, int* __restrict__ cursor,
                         const float* __restrict__ dinv,
                         int* __restrict__ csr_src, float* __restrict__ csr_nrm, int n) {
  int e = blockIdx.x * blockDim.x + threadIdx.x;
  if (e >= E) return;
  unsigned int s = (unsigned int)ei[e];
  unsigned int d = (unsigned int)ei[(size_t)E + e];
  if (s >= (unsigned int)n || d >= (unsigned int)n) return;
  int pos = row_ptr[d] + atomicAdd(&cursor[d], 1);
  csr_src[pos] = (int)s;
  csr_nrm[pos] = dinv[s] * dinv[d];
}

// ---------------- GEMM: C[M,N] = A[M,K] @ Wt[*,Kpad]^T, BM=64 tile, BK=64, single-buffered ----
// Small-LDS / high-occupancy structure (round-3 loop, ~3 blocks/CU): stage -> sync -> MFMA -> sync.
// AMODE 1: A bf16, both operands via global_load_lds. AMODE 2: A f32 -> regs -> cvt -> ds_write.
// NT_N>1: N split into NT_N col-tiles; XCD-grouped swizzle puts an M-tile's N-tiles on one XCD.
template<int BM, int BN, int TH, int NT_N, int AMODE, bool ADD_BIAS, bool DO_RELU>
__global__ __launch_bounds__(TH, 2)
void gemm6(const void* __restrict__ Av, const unsigned short* __restrict__ Bt,
           const float* __restrict__ bias, unsigned short* __restrict__ C,
           int NT_M, int M, int N, int K, int Kpad) {
  constexpr int BK = 64;
  constexpr int WN = TH / 64;             // waves, each owns WCOLS columns
  constexpr int WCOLS = BN / WN;
  constexpr int FM = BM / 16, FN = WCOLS / 16;
  constexpr int AIT = (BM * 8) / TH;
  constexpr int BIT = (BN * 8) / TH;
  constexpr int LOGN = (NT_N == 4) ? 2 : (NT_N == 2 ? 1 : 0);
  static_assert((BM * 8) % TH == 0 && (BN * 8) % TH == 0, "staging divisibility");

  // XCD-grouped grid: bid = xcd + 8*j ; j = mt_local*NT_N + nt
  const int bid = blockIdx.x;
  const int xcd = bid & 7, j = bid >> 3;
  const int per = (NT_M + 7) >> 3;
  const int mt = xcd * per + (j >> LOGN);
  const int nt = j & (NT_N - 1);
  if (mt >= NT_M) return;
  const int gm = mt * BM, gn = nt * BN;

  __shared__ __align__(16) unsigned short Alds[BM * BK];
  __shared__ __align__(16) unsigned short Blds[BN * BK];

  const int tid = threadIdx.x;
  const int wid = tid >> 6, lane = tid & 63;
  const int kg = lane >> 4, lr = lane & 15;
  const int sx = lr & 7;

  f32x4 acc[FM][FN] = {};
  f32x4 areg[AIT][2];                     // AMODE 2 staging regs

  const int nkt = Kpad / BK;
  for (int kt = 0; kt < nkt; ++kt) {
    const int k0 = kt * BK;
    // ---- stage A ----
    if constexpr (AMODE == 1) {
      const unsigned short* A = (const unsigned short*)Av;
      #pragma unroll
      for (int it = 0; it < AIT; ++it) {
        int q = it * TH + tid;
        int r = q >> 3, s = q & 7;
        int grow = gm + r; if (grow > M - 1) grow = M - 1;
        gl2lds16(A + (size_t)grow * K + k0 + ((s ^ (r & 7)) << 3), &Alds[q * 8]);
      }
    } else {
      const float* A = (const float*)Av;
      #pragma unroll
      for (int it = 0; it < AIT; ++it) {
        int q = it * TH + tid;
        int r = q >> 3, s = q & 7;
        int grow = gm + r; if (grow > M - 1) grow = M - 1;
        int kbase = k0 + (s << 3);
        int kc = (kbase + 8 <= K) ? kbase : (K - 8);
        const float* ap = A + (size_t)grow * K + kc;
        areg[it][0] = *(const f32x4*)ap;
        areg[it][1] = *(const f32x4*)(ap + 4);
      }
    }
    // ---- stage B via global_load_lds (linear dest, inverse-swizzled source) ----
    #pragma unroll
    for (int it = 0; it < BIT; ++it) {
      int q = it * TH + tid;
      int r = q >> 3, s = q & 7;
      gl2lds16(Bt + (size_t)(gn + r) * Kpad + k0 + ((s ^ (r & 7)) << 3), &Blds[q * 8]);
    }
    if constexpr (AMODE == 2) {          // cvt + swizzled ds_write (compiler counts the vmcnt)
      #pragma unroll
      for (int it = 0; it < AIT; ++it) {
        int q = it * TH + tid;
        int r = q >> 3, s = q & 7;
        int kbase = k0 + (s << 3);
        short8 b;
        #pragma unroll
        for (int i = 0; i < 4; i++) {
          b[i]     = (short)f2bf_hw(areg[it][0][i]);
          b[i + 4] = (short)f2bf_hw(areg[it][1][i]);
        }
        if (kbase + 8 > K) {             // K%8==0 -> whole slot past K
          #pragma unroll
          for (int i = 0; i < 8; i++) b[i] = 0;
        }
        *(short8*)(&Alds[(r * 8 + (s ^ (r & 7))) * 8]) = b;
      }
    }
    __syncthreads();
    // ---- fragments + MFMA (2 K-slices of 32) ----
    #pragma unroll
    for (int ks = 0; ks < 2; ++ks) {
      const int k8 = ks * 4 + kg;
      short8 af[FM], bq[FN];
      #pragma unroll
      for (int m = 0; m < FM; m++) {
        int r = m * 16 + lr;
        af[m] = *(const short8*)(&Alds[(r * 8 + (k8 ^ sx)) * 8]);
      }
      #pragma unroll
      for (int n2 = 0; n2 < FN; n2++) {
        int cc = wid * WCOLS + n2 * 16 + lr;
        bq[n2] = *(const short8*)(&Blds[(cc * 8 + (k8 ^ sx)) * 8]);
      }
      #pragma unroll
      for (int m = 0; m < FM; m++)
        #pragma unroll
        for (int n2 = 0; n2 < FN; n2++)
          acc[m][n2] = __builtin_amdgcn_mfma_f32_16x16x32_bf16(af[m], bq[n2], acc[m][n2], 0, 0, 0);
    }
    __syncthreads();
  }
  // ---- epilogue: C/D layout col=lane&15, row=(lane>>4)*4+reg ----
  #pragma unroll
  for (int m = 0; m < FM; m++) {
    #pragma unroll
    for (int jj = 0; jj < 4; jj++) {
      int grow = gm + m * 16 + kg * 4 + jj;
      if (grow < M) {
        #pragma unroll
        for (int n2 = 0; n2 < FN; n2++) {
          int gcol = gn + wid * WCOLS + n2 * 16 + lr;
          float v = acc[m][n2][jj];
          if constexpr (ADD_BIAS) v += bias[gcol];
          if constexpr (DO_RELU) v = fmaxf(v, 0.f);
          C[(size_t)grow * N + gcol] = f2bf(v);
        }
      }
    }
  }
}

// ---------------- GCN scatter (gather-by-dst via CSR), vectorized short4 ----------------
// Thread owns 4 cols. MODE 0: out = w*val ; MODE 1: out = part + (1-w)*val
template<int F, int LDH, bool DO_RELU, int MODE, bool OUT_BF16, bool PART_BF16>
__global__ __launch_bounds__(256)
void scatter_v(const unsigned short* __restrict__ h, const int* __restrict__ rp,
               const int* __restrict__ csrc, const float* __restrict__ cnrm,
               const float* __restrict__ dinv, const float* __restrict__ bias,
               const float* __restrict__ wptr, const void* __restrict__ part,
               void* __restrict__ outp, int n) {
  constexpr int TPN = F / 4;                    // threads per node
  const int tid = threadIdx.x;
  const int node = blockIdx.x * (256 / TPN) + tid / TPN;
  const int c4 = (tid % TPN) * 4;
  if (node >= n) return;
  float di = dinv[node];
  float sc = di * di;
  f32x4 acc;
  {
    short4v v = *(const short4v*)(h + (size_t)node * LDH + c4);
    acc[0] = sc * bf2f((unsigned short)v[0]);
    acc[1] = sc * bf2f((unsigned short)v[1]);
    acc[2] = sc * bf2f((unsigned short)v[2]);
    acc[3] = sc * bf2f((unsigned short)v[3]);
  }
  const int e1 = rp[node + 1];
  for (int e = rp[node]; e < e1; ++e) {
    int s = csrc[e];
    float nm = cnrm[e];
    short4v v = *(const short4v*)(h + (size_t)s * LDH + c4);
    acc[0] += nm * bf2f((unsigned short)v[0]);
    acc[1] += nm * bf2f((unsigned short)v[1]);
    acc[2] += nm * bf2f((unsigned short)v[2]);
    acc[3] += nm * bf2f((unsigned short)v[3]);
  }
  f32x4 bv = *(const f32x4*)(bias + c4);
  float w = *wptr;
  size_t idx = (size_t)node * F + c4;
  f32x4 r;
  #pragma unroll
  for (int i = 0; i < 4; i++) {
    float v = acc[i] + bv[i];
    if constexpr (DO_RELU) v = fmaxf(v, 0.f);
    if constexpr (MODE == 0) r[i] = w * v;
    else {
      float pv;
      if constexpr (PART_BF16) pv = bf2f(((const unsigned short*)part)[idx + i]);
      else pv = ((const float*)part)[idx + i];
      r[i] = pv + (1.f - w) * v;
    }
  }
  if constexpr (OUT_BF16) {
    short4v o;
    o[0] = (short)f2bf(r[0]); o[1] = (short)f2bf(r[1]);
    o[2] = (short)f2bf(r[2]); o[3] = (short)f2bf(r[3]);
    *(short4v*)((unsigned short*)outp + idx) = o;
  } else {
    *(f32x4*)((float*)outp + idx) = r;
  }
}

// ---------------- host ----------------
extern "C" void kernel_launch(void* const* d_in, const int* in_sizes, int n_in,
                              void* d_out, int out_size, void* d_ws, size_t ws_size,
                              hipStream_t stream) {
  const float* gene  = (const float*)d_in[0];
  const float* img   = (const float*)d_in[1];
  const int* ei_ge = (const int*)d_in[2];   // integers arrive as int32
  const int* ei_sp = (const int*)d_in[3];
  const float* W_fc1 = (const float*)d_in[4];  const float* b_fc1 = (const float*)d_in[5];
  const float* W_fc2 = (const float*)d_in[6];  const float* b_fc2 = (const float*)d_in[7];
  const float* W_g11 = (const float*)d_in[8];  const float* b_g11 = (const float*)d_in[9];
  const float* W_g12 = (const float*)d_in[10]; const float* b_g12 = (const float*)d_in[11];
  const float* W_g21 = (const float*)d_in[12]; const float* b_g21 = (const float*)d_in[13];
  const float* W_g22 = (const float*)d_in[14]; const float* b_g22 = (const float*)d_in[15];
  const float* w1p   = (const float*)d_in[16];
  const float* w2p   = (const float*)d_in[17];

  const int Nn = 50000;
  const int E_ge = in_sizes[2] / 2;
  const int E_sp = in_sizes[3] / 2;
  const int NT_M = CDIV(Nn, 64);             // 782 M-tiles of 64
  const int PER  = CDIV(NT_M, 8);            // 98
  const int G1   = 8 * PER;                  // swizzled grid for NT_N=1 (784)
  const int G2   = 8 * PER * 2;              // swizzled grid for NT_N=2 (1568)

  char* ws = (char*)d_ws;
  size_t off = 0;
  auto alloc = [&](size_t bytes) -> void* {
    void* p = ws + off;
    off += (bytes + 255) & ~(size_t)255;
    return p;
  };

  unsigned short* Wt1  = (unsigned short*)alloc((size_t)512 * 3008 * 2);
  unsigned short* Wt2  = (unsigned short*)alloc((size_t)512 * 1024 * 2);
  unsigned short* Wt11 = (unsigned short*)alloc((size_t)256 * 512 * 2);
  unsigned short* Wt12 = (unsigned short*)alloc((size_t)256 * 512 * 2);
  unsigned short* WtC  = (unsigned short*)alloc((size_t)128 * 256 * 2);  // [W_g21 | W_g22] rows
  int*   deg_sp  = (int*)alloc((size_t)Nn * 4);
  int*   deg_ge  = (int*)alloc((size_t)Nn * 4);
  float* dinv_sp = (float*)alloc((size_t)Nn * 4);
  float* dinv_ge = (float*)alloc((size_t)Nn * 4);
  int*   rp_sp   = (int*)alloc((size_t)(Nn + 1) * 4);
  int*   rp_ge   = (int*)alloc((size_t)(Nn + 1) * 4);
  int*   cursor  = (int*)alloc((size_t)Nn * 4);
  int*   csrc_sp = (int*)alloc((size_t)E_sp * 4);
  float* cnrm_sp = (float*)alloc((size_t)E_sp * 4);
  int*   csrc_ge = (int*)alloc((size_t)E_ge * 4);
  float* cnrm_ge = (float*)alloc((size_t)E_ge * 4);
  unsigned short* xbuf  = (unsigned short*)alloc((size_t)Nn * 512 * 2);  // x1 / x2, later Xc
  unsigned short* tmp   = (unsigned short*)alloc((size_t)Nn * 256 * 2);  // GEMM out pre-scatter (bf16)
  unsigned short* xpart = (unsigned short*)alloc((size_t)Nn * 256 * 2);  // bf16 part; fp32 64-col part fits
  unsigned short* Xc = xbuf;
  unsigned short* tmp2 = tmp;
  (void)ws_size; (void)n_in; (void)out_size;

  // 1. weight transposes (bf16, K zero-padded)
  transpose_w<<<dim3(94, 16), 256, 0, stream>>>(W_fc1, Wt1, 3000, 512, 3008);
  transpose_w<<<dim3(32, 16), 256, 0, stream>>>(W_fc2, Wt2, 1024, 512, 1024);
  transpose_w<<<dim3(16, 8),  256, 0, stream>>>(W_g11, Wt11, 512, 256, 512);
  transpose_w<<<dim3(16, 8),  256, 0, stream>>>(W_g12, Wt12, 512, 256, 512);
  transpose_w<<<dim3(8, 2),   256, 0, stream>>>(W_g21, WtC, 256, 64, 256);
  transpose_w<<<dim3(8, 2),   256, 0, stream>>>(W_g22, WtC + (size_t)64 * 256, 256, 64, 256);

  // 2. graph prep
  deg_init<<<CDIV(Nn, 256), 256, 0, stream>>>(deg_sp, deg_ge, Nn);
  deg_hist<<<CDIV(E_sp, 256), 256, 0, stream>>>(ei_sp, E_sp, deg_sp, Nn);
  deg_hist<<<CDIV(E_ge, 256), 256, 0, stream>>>(ei_ge, E_ge, deg_ge, Nn);
  dinv_k<<<CDIV(Nn, 256), 256, 0, stream>>>(deg_sp, dinv_sp, Nn);
  dinv_k<<<CDIV(Nn, 256), 256, 0, stream>>>(deg_ge, dinv_ge, Nn);
  scan_rowptr<<<1, 1024, 0, stream>>>(deg_sp, rp_sp, Nn);
  scan_rowptr<<<1, 1024, 0, stream>>>(deg_ge, rp_ge, Nn);
  zero_i32<<<CDIV(Nn, 256), 256, 0, stream>>>(cursor, Nn);
  csr_fill<<<CDIV(E_sp, 256), 256, 0, stream>>>(ei_sp, E_sp, rp_sp, cursor, dinv_sp, csrc_sp, cnrm_sp, Nn);
  zero_i32<<<CDIV(Nn, 256), 256, 0, stream>>>(cursor, Nn);
  csr_fill<<<CDIV(E_ge, 256), 256, 0, stream>>>(ei_ge, E_ge, rp_ge, cursor, dinv_ge, csrc_ge, cnrm_ge, Nn);

  // 3. x1 = relu(gene @ W_fc1 + b) -> bf16   (64x256 tiles, NT_N=2, inline f32->bf16)
  gemm6<64, 256, 256, 2, 2, true, true><<<G2, 256, 0, stream>>>(
      gene, Wt1, b_fc1, xbuf, NT_M, Nn, 512, 3000, 3008);
  // 4. tmp = x1 @ W_g11 (bf16, both operands gl2lds, full-N=256)
  gemm6<64, 256, 256, 1, 1, false, false><<<G1, 256, 0, stream>>>(
      xbuf, Wt11, nullptr, tmp, NT_M, Nn, 256, 512, 512);
  // 5. xpart = bf16( w1 * relu(gcn_sp(tmp) + b_g11) )
  scatter_v<256, 256, true, 0, true, false><<<Nn / 4, 256, 0, stream>>>(
      tmp, rp_sp, csrc_sp, cnrm_sp, dinv_sp, b_g11, w1p, nullptr, xpart, Nn);
  // 6. x2 = relu(img @ W_fc2 + b) -> bf16 (reuse xbuf)
  gemm6<64, 256, 256, 2, 2, true, true><<<G2, 256, 0, stream>>>(
      img, Wt2, b_fc2, xbuf, NT_M, Nn, 512, 1024, 1024);
  // 7. tmp = x2 @ W_g12
  gemm6<64, 256, 256, 1, 1, false, false><<<G1, 256, 0, stream>>>(
      xbuf, Wt12, nullptr, tmp, Nn ? NT_M : NT_M, Nn, 256, 512, 512);
  // 8. Xc = bf16(xpart + (1-w1) * relu(gcn_ge(tmp) + b_g12))   [Xc aliases xbuf]
  scatter_v<256, 256, true, 1, true, true><<<Nn / 4, 256, 0, stream>>>(
      tmp, rp_ge, csrc_ge, cnrm_ge, dinv_ge, b_g12, w1p, xpart, Xc, Nn);
  // 9+11. tmp2 = Xc @ [W_g21 | W_g22]  (N=128, one pass over Xc; WCOLS=32)
  gemm6<64, 128, 256, 1, 1, false, false><<<G1, 256, 0, stream>>>(
      Xc, WtC, nullptr, tmp2, NT_M, Nn, 128, 256, 256);
  // 10. xpart(fp32) = w2 * (gcn_sp(tmp2[:, 0:64]) + b_g21)
  scatter_v<64, 128, false, 0, false, false><<<Nn / 16, 256, 0, stream>>>(
      tmp2, rp_sp, csrc_sp, cnrm_sp, dinv_sp, b_g21, w2p, nullptr, (float*)xpart, Nn);
  // 12. d_out = xpart + (1-w2) * (gcn_ge(tmp2[:, 64:128]) + b_g22)
  scatter_v<64, 128, false, 1, false, false><<<Nn / 16, 256, 0, stream>>>(
      tmp2 + 64, rp_ge, csrc_ge, cnrm_ge, dinv_ge, b_g22, w2p, (float*)xpart, d_out, Nn);
}

// Round 8
// 901.859 us; speedup vs baseline: 1.1080x; 1.0063x over previous
//
#include <hip/hip_runtime.h>
#include <hip/hip_bf16.h>
#include <stdint.h>

typedef __attribute__((ext_vector_type(4))) float f32x4;
typedef __attribute__((ext_vector_type(8))) short short8;
typedef __attribute__((ext_vector_type(4))) short short4v;

#define CDIV(a, b) (((a) + (b) - 1) / (b))

__device__ __forceinline__ unsigned short f2bf(float x) {
  union { float f; unsigned int u; } c; c.f = x;
  unsigned int r = c.u + 0x7FFFu + ((c.u >> 16) & 1u);   // round-to-nearest-even
  return (unsigned short)(r >> 16);
}
__device__ __forceinline__ unsigned short f2bf_hw(float x) {
  __hip_bfloat16 h = __float2bfloat16(x);                // pairs fuse into v_cvt_pk_bf16_f32
  unsigned short u; __builtin_memcpy(&u, &h, 2); return u;
}
__device__ __forceinline__ float bf2f(unsigned short b) {
  union { unsigned int u; float f; } c; c.u = (unsigned int)b << 16; return c.f;
}

// async global->LDS, 16B per lane; LDS dest must be wave-uniform base + lane*16 (linear)
__device__ __forceinline__ void gl2lds16(const void* g, void* lds) {
  __builtin_amdgcn_global_load_lds(
      reinterpret_cast<const __attribute__((address_space(1))) unsigned int*>(
          reinterpret_cast<uintptr_t>(g)),
      reinterpret_cast<__attribute__((address_space(3))) unsigned int*>(
          reinterpret_cast<uintptr_t>(lds)),
      16, 0, 0);
}

// ---------------- weight transpose: W[K][N] f32 -> Wt[N][Kpad] bf16, zero-padded ----------------
__global__ void transpose_w(const float* __restrict__ W, unsigned short* __restrict__ Wt,
                            int K, int N, int Kpad) {
  __shared__ float tile[32][33];
  int kb = blockIdx.x * 32, nb = blockIdx.y * 32;
  int tx = threadIdx.x & 31, ty = threadIdx.x >> 5;  // 256 threads = 32x8
  for (int r = ty; r < 32; r += 8) {
    int k = kb + r, n = nb + tx;
    tile[r][tx] = (k < K && n < N) ? W[(size_t)k * N + n] : 0.f;
  }
  __syncthreads();
  for (int r = ty; r < 32; r += 8) {
    int n = nb + r, k = kb + tx;
    if (n < N && k < Kpad) Wt[(size_t)n * Kpad + k] = f2bf(tile[tx][r]);
  }
}

// ---------------- graph prep ----------------
__global__ void zero_i32(int* __restrict__ p, int n) {
  int i = blockIdx.x * blockDim.x + threadIdx.x;
  if (i < n) p[i] = 0;
}

__global__ void deg_init(int* __restrict__ a, int* __restrict__ b, int n) {
  int i = blockIdx.x * blockDim.x + threadIdx.x;
  if (i < n) { a[i] = 1; b[i] = 1; }   // self-loop
}

__global__ void deg_hist(const int* __restrict__ ei, int E, int* __restrict__ deg, int n) {
  int e = blockIdx.x * blockDim.x + threadIdx.x;
  if (e >= E) return;
  unsigned int d = (unsigned int)ei[(size_t)E + e];
  if (d < (unsigned int)n) atomicAdd(&deg[d], 1);
}

__global__ void dinv_k(const int* __restrict__ deg, float* __restrict__ dinv, int n) {
  int i = blockIdx.x * blockDim.x + threadIdx.x;
  if (i < n) dinv[i] = rsqrtf((float)deg[i]);
}

// exclusive scan of (deg-1) -> row_ptr[0..n], single block of 1024, shfl-based
__global__ void scan_rowptr(const int* __restrict__ deg, int* __restrict__ rp, int n) {
  __shared__ int wsum[16];
  __shared__ int carry_s;
  const int tid = threadIdx.x, lane = tid & 63, w = tid >> 6;
  if (tid == 0) carry_s = 0;
  __syncthreads();
  for (int base = 0; base < n; base += 1024) {
    int i = base + tid;
    int d = (i < n) ? (deg[i] - 1) : 0;
    int v = d;
    #pragma unroll
    for (int off = 1; off < 64; off <<= 1) {
      int t = __shfl_up(v, off, 64);
      if (lane >= off) v += t;
    }
    if (lane == 63) wsum[w] = v;
    __syncthreads();
    int carry = carry_s;
    if (w == 0) {
      int s = (lane < 16) ? wsum[lane] : 0;
      #pragma unroll
      for (int off = 1; off < 16; off <<= 1) {
        int t = __shfl_up(s, off, 64);
        if (lane >= off) s += t;
      }
      if (lane < 16) wsum[lane] = s;
    }
    __syncthreads();
    int woff = (w > 0) ? wsum[w - 1] : 0;
    if (i < n) rp[i] = carry + woff + v - d;
    if (tid == 0) carry_s = carry + wsum[15];
    __syncthreads();
  }
  if (threadIdx.x == 0) rp[n] = carry_s;
}

__global__ void csr_fill(const int* __restrict__ ei, int E,
                         const int* __restrict__ row_ptr, int* __restrict__ cursor,
                         const float* __restrict__ dinv,
                         int* __restrict__ csr_src, float* __restrict__ csr_nrm, int n) {
  int e = blockIdx.x * blockDim.x + threadIdx.x;
  if (e >= E) return;
  unsigned int s = (unsigned int)ei[e];
  unsigned int d = (unsigned int)ei[(size_t)E + e];
  if (s >= (unsigned int)n || d >= (unsigned int)n) return;
  int pos = row_ptr[d] + atomicAdd(&cursor[d], 1);
  csr_src[pos] = (int)s;
  csr_nrm[pos] = dinv[s] * dinv[d];
}

// ---------------- GEMM: C[M,N] = A[M,K] @ Wt[*,Kpad]^T, BM=64, BK=64, single-buffered ----
// Round-7 loop structure (highest measured). AMODE 1: A bf16 via gl2lds.
// AMODE 3: A f32 staged RAW via gl2lds (16 slots/row, XOR swizzle), bf16 convert at
// fragment read; K-tail (K%64!=0, K%4==0) via reg-staged masked path.
// NT_N>1: XCD-grouped swizzle puts one M-tile's N-tiles on one XCD (A L2-resident).
template<int BM, int BN, int TH, int NT_N, int AMODE, bool ADD_BIAS, bool DO_RELU>
__global__ __launch_bounds__(TH, 2)
void gemm7(const void* __restrict__ Av, const unsigned short* __restrict__ Bt,
           const float* __restrict__ bias, unsigned short* __restrict__ C,
           int NT_M, int M, int N, int K, int Kpad) {
  constexpr int BK = 64;
  constexpr int WN = TH / 64;
  constexpr int WCOLS = BN / WN;
  constexpr int FM = BM / 16, FN = WCOLS / 16;
  constexpr int BIT = (BN * 8) / TH;
  constexpr int AIT1 = (BM * 8) / TH;      // bf16 A: 16B chunks/thread
  constexpr int AIT3 = (BM * 16) / TH;     // f32  A: 16B chunks/thread
  constexpr int LOGN = (NT_N == 4) ? 2 : (NT_N == 2 ? 1 : 0);
  static_assert((BM * 8) % TH == 0 && (BN * 8) % TH == 0, "staging divisibility");

  const int bid = blockIdx.x;
  const int xcd = bid & 7, j = bid >> 3;
  const int per = (NT_M + 7) >> 3;
  const int mt = xcd * per + (j >> LOGN);
  const int nt = j & (NT_N - 1);
  if (mt >= NT_M) return;
  const int gm = mt * BM, gn = nt * BN;

  constexpr int ABYTES = (AMODE == 3) ? BM * BK * 4 : BM * BK * 2;
  __shared__ __align__(16) char AldsRaw[ABYTES];
  __shared__ __align__(16) unsigned short Blds[BN * BK];

  const int tid = threadIdx.x;
  const int wid = tid >> 6, lane = tid & 63;
  const int kg = lane >> 4, lr = lane & 15;
  const int sx = lr & 7;

  f32x4 acc[FM][FN] = {};

  const int nkt = Kpad / BK;
  for (int kt = 0; kt < nkt; ++kt) {
    const int k0 = kt * BK;
    // ---- stage A ----
    if constexpr (AMODE == 1) {
      const unsigned short* A = (const unsigned short*)Av;
      unsigned short* Alds = (unsigned short*)AldsRaw;
      #pragma unroll
      for (int it = 0; it < AIT1; ++it) {
        int q = it * TH + tid;
        int r = q >> 3, s = q & 7;
        int grow = gm + r; if (grow > M - 1) grow = M - 1;
        gl2lds16(A + (size_t)grow * K + k0 + ((s ^ (r & 7)) << 3), &Alds[q * 8]);
      }
    } else {  // AMODE 3: raw f32, 16 slots/row, swizzled source
      const float* A = (const float*)Av;
      float* Af = (float*)AldsRaw;
      if (k0 + BK <= K) {
        #pragma unroll
        for (int it = 0; it < AIT3; ++it) {
          int q = it * TH + tid;
          int r = q >> 4, s = q & 15;
          int grow = gm + r; if (grow > M - 1) grow = M - 1;
          gl2lds16(A + (size_t)grow * K + k0 + ((s ^ (r & 15)) << 2), &Af[q * 4]);
        }
      } else {  // tail: reg-staged, zero-masked (K%4==0 -> slots all-valid or all-invalid)
        #pragma unroll
        for (int it = 0; it < AIT3; ++it) {
          int q = it * TH + tid;
          int r = q >> 4, s = q & 15;
          int grow = gm + r; if (grow > M - 1) grow = M - 1;
          int kbase = k0 + ((s ^ (r & 15)) << 2);
          f32x4 v = {0.f, 0.f, 0.f, 0.f};
          if (kbase + 4 <= K) v = *(const f32x4*)(A + (size_t)grow * K + kbase);
          *(f32x4*)(&Af[q * 4]) = v;
        }
      }
    }
    // ---- stage B via global_load_lds (linear dest, inverse-swizzled source) ----
    #pragma unroll
    for (int it = 0; it < BIT; ++it) {
      int q = it * TH + tid;
      int r = q >> 3, s = q & 7;
      gl2lds16(Bt + (size_t)(gn + r) * Kpad + k0 + ((s ^ (r & 7)) << 3), &Blds[q * 8]);
    }
    __syncthreads();
    // ---- fragments + MFMA (2 K-slices of 32) ----
    #pragma unroll
    for (int ks = 0; ks < 2; ++ks) {
      const int k8 = ks * 4 + kg;
      short8 af[FM], bq[FN];
      #pragma unroll
      for (int m = 0; m < FM; m++) {
        int r = m * 16 + lr;
        if constexpr (AMODE == 1) {
          const unsigned short* Alds = (const unsigned short*)AldsRaw;
          af[m] = *(const short8*)(&Alds[(r * 8 + (k8 ^ sx)) * 8]);
        } else {
          const float* Af = (const float*)AldsRaw;
          int s0 = (2 * k8) ^ lr, s1 = (2 * k8 + 1) ^ lr;
          f32x4 lo = *(const f32x4*)(Af + r * 64 + s0 * 4);
          f32x4 hi = *(const f32x4*)(Af + r * 64 + s1 * 4);
          #pragma unroll
          for (int i = 0; i < 4; i++) {
            af[m][i]     = (short)f2bf_hw(lo[i]);
            af[m][i + 4] = (short)f2bf_hw(hi[i]);
          }
        }
      }
      #pragma unroll
      for (int n2 = 0; n2 < FN; n2++) {
        int cc = wid * WCOLS + n2 * 16 + lr;
        bq[n2] = *(const short8*)(&Blds[(cc * 8 + (k8 ^ sx)) * 8]);
      }
      #pragma unroll
      for (int m = 0; m < FM; m++)
        #pragma unroll
        for (int n2 = 0; n2 < FN; n2++)
          acc[m][n2] = __builtin_amdgcn_mfma_f32_16x16x32_bf16(af[m], bq[n2], acc[m][n2], 0, 0, 0);
    }
    __syncthreads();
  }
  // ---- epilogue: C/D layout col=lane&15, row=(lane>>4)*4+reg ----
  #pragma unroll
  for (int m = 0; m < FM; m++) {
    #pragma unroll
    for (int jj = 0; jj < 4; jj++) {
      int grow = gm + m * 16 + kg * 4 + jj;
      if (grow < M) {
        #pragma unroll
        for (int n2 = 0; n2 < FN; n2++) {
          int gcol = gn + wid * WCOLS + n2 * 16 + lr;
          float v = acc[m][n2][jj];
          if constexpr (ADD_BIAS) v += bias[gcol];
          if constexpr (DO_RELU) v = fmaxf(v, 0.f);
          C[(size_t)grow * N + gcol] = f2bf(v);
        }
      }
    }
  }
}

// ---------------- GCN scatter (gather-by-dst via CSR), short4 + 2-way unrolled edge loop ----
// Thread owns 4 cols. MODE 0: out = w*val ; MODE 1: out = part + (1-w)*val
template<int F, int LDH, bool DO_RELU, int MODE, bool OUT_BF16, bool PART_BF16>
__global__ __launch_bounds__(256)
void scatter_v(const unsigned short* __restrict__ h, const int* __restrict__ rp,
               const int* __restrict__ csrc, const float* __restrict__ cnrm,
               const float* __restrict__ dinv, const float* __restrict__ bias,
               const float* __restrict__ wptr, const void* __restrict__ part,
               void* __restrict__ outp, int n) {
  constexpr int TPN = F / 4;                    // threads per node
  const int tid = threadIdx.x;
  const int node = blockIdx.x * (256 / TPN) + tid / TPN;
  const int c4 = (tid % TPN) * 4;
  if (node >= n) return;
  float di = dinv[node];
  float sc = di * di;
  f32x4 acc, acc2 = {0.f, 0.f, 0.f, 0.f};
  {
    short4v v = *(const short4v*)(h + (size_t)node * LDH + c4);
    acc[0] = sc * bf2f((unsigned short)v[0]);
    acc[1] = sc * bf2f((unsigned short)v[1]);
    acc[2] = sc * bf2f((unsigned short)v[2]);
    acc[3] = sc * bf2f((unsigned short)v[3]);
  }
  const int e0 = rp[node], e1 = rp[node + 1];
  int e = e0;
  for (; e + 2 <= e1; e += 2) {                 // 2-way MLP: two independent gathers in flight
    int s0 = csrc[e], s1 = csrc[e + 1];
    float n0 = cnrm[e], n1 = cnrm[e + 1];
    short4v v0 = *(const short4v*)(h + (size_t)s0 * LDH + c4);
    short4v v1 = *(const short4v*)(h + (size_t)s1 * LDH + c4);
    acc[0]  += n0 * bf2f((unsigned short)v0[0]);
    acc[1]  += n0 * bf2f((unsigned short)v0[1]);
    acc[2]  += n0 * bf2f((unsigned short)v0[2]);
    acc[3]  += n0 * bf2f((unsigned short)v0[3]);
    acc2[0] += n1 * bf2f((unsigned short)v1[0]);
    acc2[1] += n1 * bf2f((unsigned short)v1[1]);
    acc2[2] += n1 * bf2f((unsigned short)v1[2]);
    acc2[3] += n1 * bf2f((unsigned short)v1[3]);
  }
  if (e < e1) {
    int s0 = csrc[e];
    float n0 = cnrm[e];
    short4v v0 = *(const short4v*)(h + (size_t)s0 * LDH + c4);
    acc[0] += n0 * bf2f((unsigned short)v0[0]);
    acc[1] += n0 * bf2f((unsigned short)v0[1]);
    acc[2] += n0 * bf2f((unsigned short)v0[2]);
    acc[3] += n0 * bf2f((unsigned short)v0[3]);
  }
  #pragma unroll
  for (int i = 0; i < 4; i++) acc[i] += acc2[i];
  f32x4 bv = *(const f32x4*)(bias + c4);
  float w = *wptr;
  size_t idx = (size_t)node * F + c4;
  f32x4 r;
  #pragma unroll
  for (int i = 0; i < 4; i++) {
    float v = acc[i] + bv[i];
    if constexpr (DO_RELU) v = fmaxf(v, 0.f);
    if constexpr (MODE == 0) r[i] = w * v;
    else {
      float pv;
      if constexpr (PART_BF16) pv = bf2f(((const unsigned short*)part)[idx + i]);
      else pv = ((const float*)part)[idx + i];
      r[i] = pv + (1.f - w) * v;
    }
  }
  if constexpr (OUT_BF16) {
    short4v o;
    o[0] = (short)f2bf(r[0]); o[1] = (short)f2bf(r[1]);
    o[2] = (short)f2bf(r[2]); o[3] = (short)f2bf(r[3]);
    *(short4v*)((unsigned short*)outp + idx) = o;
  } else {
    *(f32x4*)((float*)outp + idx) = r;
  }
}

// ---------------- host ----------------
extern "C" void kernel_launch(void* const* d_in, const int* in_sizes, int n_in,
                              void* d_out, int out_size, void* d_ws, size_t ws_size,
                              hipStream_t stream) {
  const float* gene  = (const float*)d_in[0];
  const float* img   = (const float*)d_in[1];
  const int* ei_ge = (const int*)d_in[2];   // integers arrive as int32
  const int* ei_sp = (const int*)d_in[3];
  const float* W_fc1 = (const float*)d_in[4];  const float* b_fc1 = (const float*)d_in[5];
  const float* W_fc2 = (const float*)d_in[6];  const float* b_fc2 = (const float*)d_in[7];
  const float* W_g11 = (const float*)d_in[8];  const float* b_g11 = (const float*)d_in[9];
  const float* W_g12 = (const float*)d_in[10]; const float* b_g12 = (const float*)d_in[11];
  const float* W_g21 = (const float*)d_in[12]; const float* b_g21 = (const float*)d_in[13];
  const float* W_g22 = (const float*)d_in[14]; const float* b_g22 = (const float*)d_in[15];
  const float* w1p   = (const float*)d_in[16];
  const float* w2p   = (const float*)d_in[17];

  const int Nn = 50000;
  const int E_ge = in_sizes[2] / 2;
  const int E_sp = in_sizes[3] / 2;
  const int NT_M = CDIV(Nn, 64);             // 782 M-tiles of 64
  const int PER  = CDIV(NT_M, 8);            // 98
  const int G1   = 8 * PER;                  // swizzled grid, NT_N=1
  const int G2   = 8 * PER * 2;              // swizzled grid, NT_N=2

  char* ws = (char*)d_ws;
  size_t off = 0;
  auto alloc = [&](size_t bytes) -> void* {
    void* p = ws + off;
    off += (bytes + 255) & ~(size_t)255;
    return p;
  };

  unsigned short* Wt1  = (unsigned short*)alloc((size_t)512 * 3008 * 2);
  unsigned short* Wt2  = (unsigned short*)alloc((size_t)512 * 1024 * 2);
  unsigned short* Wt11 = (unsigned short*)alloc((size_t)256 * 512 * 2);
  unsigned short* Wt12 = (unsigned short*)alloc((size_t)256 * 512 * 2);
  unsigned short* WtC  = (unsigned short*)alloc((size_t)128 * 256 * 2);  // [W_g21 | W_g22] rows
  int*   deg_sp  = (int*)alloc((size_t)Nn * 4);
  int*   deg_ge  = (int*)alloc((size_t)Nn * 4);
  float* dinv_sp = (float*)alloc((size_t)Nn * 4);
  float* dinv_ge = (float*)alloc((size_t)Nn * 4);
  int*   rp_sp   = (int*)alloc((size_t)(Nn + 1) * 4);
  int*   rp_ge   = (int*)alloc((size_t)(Nn + 1) * 4);
  int*   cursor  = (int*)alloc((size_t)Nn * 4);
  int*   csrc_sp = (int*)alloc((size_t)E_sp * 4);
  float* cnrm_sp = (float*)alloc((size_t)E_sp * 4);
  int*   csrc_ge = (int*)alloc((size_t)E_ge * 4);
  float* cnrm_ge = (float*)alloc((size_t)E_ge * 4);
  unsigned short* xbuf  = (unsigned short*)alloc((size_t)Nn * 512 * 2);  // x1 / x2, later Xc
  unsigned short* tmp   = (unsigned short*)alloc((size_t)Nn * 256 * 2);  // GEMM out pre-scatter (bf16)
  unsigned short* xpart = (unsigned short*)alloc((size_t)Nn * 256 * 2);  // bf16 part; fp32 64-col part fits
  unsigned short* Xc = xbuf;
  unsigned short* tmp2 = tmp;
  (void)ws_size; (void)n_in; (void)out_size;

  // 1. weight transposes (bf16, K zero-padded)
  transpose_w<<<dim3(94, 16), 256, 0, stream>>>(W_fc1, Wt1, 3000, 512, 3008);
  transpose_w<<<dim3(32, 16), 256, 0, stream>>>(W_fc2, Wt2, 1024, 512, 1024);
  transpose_w<<<dim3(16, 8),  256, 0, stream>>>(W_g11, Wt11, 512, 256, 512);
  transpose_w<<<dim3(16, 8),  256, 0, stream>>>(W_g12, Wt12, 512, 256, 512);
  transpose_w<<<dim3(8, 2),   256, 0, stream>>>(W_g21, WtC, 256, 64, 256);
  transpose_w<<<dim3(8, 2),   256, 0, stream>>>(W_g22, WtC + (size_t)64 * 256, 256, 64, 256);

  // 2. graph prep
  deg_init<<<CDIV(Nn, 256), 256, 0, stream>>>(deg_sp, deg_ge, Nn);
  deg_hist<<<CDIV(E_sp, 256), 256, 0, stream>>>(ei_sp, E_sp, deg_sp, Nn);
  deg_hist<<<CDIV(E_ge, 256), 256, 0, stream>>>(ei_ge, E_ge, deg_ge, Nn);
  dinv_k<<<CDIV(Nn, 256), 256, 0, stream>>>(deg_sp, dinv_sp, Nn);
  dinv_k<<<CDIV(Nn, 256), 256, 0, stream>>>(deg_ge, dinv_ge, Nn);
  scan_rowptr<<<1, 1024, 0, stream>>>(deg_sp, rp_sp, Nn);
  scan_rowptr<<<1, 1024, 0, stream>>>(deg_ge, rp_ge, Nn);
  zero_i32<<<CDIV(Nn, 256), 256, 0, stream>>>(cursor, Nn);
  csr_fill<<<CDIV(E_sp, 256), 256, 0, stream>>>(ei_sp, E_sp, rp_sp, cursor, dinv_sp, csrc_sp, cnrm_sp, Nn);
  zero_i32<<<CDIV(Nn, 256), 256, 0, stream>>>(cursor, Nn);
  csr_fill<<<CDIV(E_ge, 256), 256, 0, stream>>>(ei_ge, E_ge, rp_ge, cursor, dinv_ge, csrc_ge, cnrm_ge, Nn);

  // 3. x1 = relu(gene @ W_fc1 + b) -> bf16   (64x256, NT_N=2, raw-f32-A gl2lds + cvt@read)
  gemm7<64, 256, 256, 2, 3, true, true><<<G2, 256, 0, stream>>>(
      gene, Wt1, b_fc1, xbuf, NT_M, Nn, 512, 3000, 3008);
  // 4. tmp = x1 @ W_g11 (bf16, both operands gl2lds, full-N=256)
  gemm7<64, 256, 256, 1, 1, false, false><<<G1, 256, 0, stream>>>(
      xbuf, Wt11, nullptr, tmp, NT_M, Nn, 256, 512, 512);
  // 5. xpart = bf16( w1 * relu(gcn_sp(tmp) + b_g11) )
  scatter_v<256, 256, true, 0, true, false><<<Nn / 4, 256, 0, stream>>>(
      tmp, rp_sp, csrc_sp, cnrm_sp, dinv_sp, b_g11, w1p, nullptr, xpart, Nn);
  // 6. x2 = relu(img @ W_fc2 + b) -> bf16 (reuse xbuf; K=1024, no tail)
  gemm7<64, 256, 256, 2, 3, true, true><<<G2, 256, 0, stream>>>(
      img, Wt2, b_fc2, xbuf, NT_M, Nn, 512, 1024, 1024);
  // 7. tmp = x2 @ W_g12
  gemm7<64, 256, 256, 1, 1, false, false><<<G1, 256, 0, stream>>>(
      xbuf, Wt12, nullptr, tmp, NT_M, Nn, 256, 512, 512);
  // 8. Xc = bf16(xpart + (1-w1) * relu(gcn_ge(tmp) + b_g12))   [Xc aliases xbuf]
  scatter_v<256, 256, true, 1, true, true><<<Nn / 4, 256, 0, stream>>>(
      tmp, rp_ge, csrc_ge, cnrm_ge, dinv_ge, b_g12, w1p, xpart, Xc, Nn);
  // 9+11. tmp2 = Xc @ [W_g21 | W_g22]  (N=128, one pass over Xc)
  gemm7<64, 128, 256, 1, 1, false, false><<<G1, 256, 0, stream>>>(
      Xc, WtC, nullptr, tmp2, NT_M, Nn, 128, 256, 256);
  // 10. xpart(fp32) = w2 * (gcn_sp(tmp2[:, 0:64]) + b_g21)
  scatter_v<64, 128, false, 0, false, false><<<Nn / 16, 256, 0, stream>>>(
      tmp2, rp_sp, csrc_sp, cnrm_sp, dinv_sp, b_g21, w2p, nullptr, (float*)xpart, Nn);
  // 12. d_out = xpart + (1-w2) * (gcn_ge(tmp2[:, 64:128]) + b_g22)
  scatter_v<64, 128, false, 1, false, false><<<Nn / 16, 256, 0, stream>>>(
      tmp2 + 64, rp_ge, csrc_ge, cnrm_ge, dinv_ge, b_g22, w2p, (float*)xpart, d_out, Nn);
}